// Round 1
// baseline (316.401 us; speedup 1.0000x reference)
//
#include <hip/hip_runtime.h>

#define EPSN 1e-12f

// One block handles (n, h, x-tile of TX=64). Computes out[n, j, h, x] for all
// j in [0,D), x in tile. Banded matmul over channels C with L2-normalized
// columns. Output layout: (N, D, H, W).
template<int C, int H, int W, int D, int TX, int NT>
__global__ __launch_bounds__(NT)
void cost_volume_kernel(const float* __restrict__ Lp, const float* __restrict__ Rp,
                        float* __restrict__ out)
{
    static_assert(TX == 64, "tile decode hardcodes TX=64");
    constexpr int RS = TX + D;              // staged r width: y in [X0-D, X0+TX)
    constexpr int NTILES = (TX / 4) * (D / 4);

    __shared__ __align__(16) float ls[C * TX];
    __shared__ __align__(16) float rs[C * RS];

    const int tid = threadIdx.x;
    const int bx  = blockIdx.x;
    constexpr int NXB = W / TX;
    const int xb  = bx % NXB;
    const int h   = (bx / NXB) % H;
    const int n   = bx / (NXB * H);
    const int X0  = xb * TX;
    const int Yb  = X0 - D;

    // ---- stage left tile: C rows x TX floats, float4 coalesced ----
    {
        constexpr int NV = C * TX / 4;
        for (int i = tid; i < NV; i += NT) {
            const int c = i / (TX / 4);
            const int v = i % (TX / 4);
            const float4 val =
                *(const float4*)&Lp[(((size_t)n * C + c) * H + h) * W + X0 + 4 * v];
            *(float4*)&ls[c * TX + 4 * v] = val;
        }
    }
    // ---- stage right tile: C rows x RS floats, zero-fill y<0 ----
    {
        constexpr int NV = C * RS / 4;
        for (int i = tid; i < NV; i += NT) {
            const int c = i / (RS / 4);
            const int v = i % (RS / 4);
            const int y = Yb + 4 * v;
            const float* src = &Rp[(((size_t)n * C + c) * H + h) * W];
            float4 val;
            if (y >= 0) {
                val = *(const float4*)&src[y];
            } else {
                val.x = (y + 0) >= 0 ? src[y + 0] : 0.f;
                val.y = (y + 1) >= 0 ? src[y + 1] : 0.f;
                val.z = (y + 2) >= 0 ? src[y + 2] : 0.f;
                val.w = (y + 3) >= 0 ? src[y + 3] : 0.f;
            }
            *(float4*)&rs[c * RS + 4 * v] = val;
        }
    }
    __syncthreads();

    // ---- in-place L2 normalization, one column per thread ----
    // column stride (TX or RS) is ≡ 0 mod 32 floats -> lanes hit distinct
    // banks by column index; 2-way aliasing only (free).
    for (int col = tid; col < TX + RS; col += NT) {
        float* base;
        int stride;
        if (col < TX) { base = &ls[col];       stride = TX; }
        else          { base = &rs[col - TX];  stride = RS; }
        float s = 0.f;
        #pragma unroll 8
        for (int c = 0; c < C; ++c) { const float v = base[c * stride]; s += v * v; }
        const float inv = 1.0f / fmaxf(sqrtf(s), EPSN);
        #pragma unroll 8
        for (int c = 0; c < C; ++c) base[c * stride] *= inv;
    }
    __syncthreads();

    // ---- compute: each tile t = (tj, gx) is a 4x4 (j,x) register block ----
    // gx fast in tid -> 16 consecutive lanes span one 64-float output row:
    // float4 stores fully coalesced (4x 256B contiguous segments per wave).
    for (int t = tid; t < NTILES; t += NT) {
        const int gx = t & 15;          // x group: x = X0 + 4*gx + dx
        const int tj = t >> 4;          // j group: j = 4*tj + jp
        // r window: y = x - j spans [4gx-4tj-3, 4gx-4tj+3] + X0;
        // in rs coords (ys = y - Yb = y - X0 + D): base = D + 4(gx-tj) - 4,
        // read 8 floats (4-aligned), used indices 1..7.
        const int rbase = D + 4 * (gx - tj) - 4;

        float acc[4][4];
        #pragma unroll
        for (int a = 0; a < 4; ++a)
            #pragma unroll
            for (int b = 0; b < 4; ++b) acc[a][b] = 0.f;

        #pragma unroll 4
        for (int c = 0; c < C; ++c) {
            const float4 lv = *(const float4*)&ls[c * TX + 4 * gx];
            const float4 r0 = *(const float4*)&rs[c * RS + rbase];
            const float4 r1 = *(const float4*)&rs[c * RS + rbase + 4];
            const float lf[4] = {lv.x, lv.y, lv.z, lv.w};
            const float rf[8] = {r0.x, r0.y, r0.z, r0.w, r1.x, r1.y, r1.z, r1.w};
            #pragma unroll
            for (int jp = 0; jp < 4; ++jp)
                #pragma unroll
                for (int dx = 0; dx < 4; ++dx)
                    acc[jp][dx] = fmaf(lf[dx], rf[4 + dx - jp], acc[jp][dx]);
        }

        const int j0 = 4 * tj;
        float* orow = &out[(((size_t)n * D + j0) * H + h) * W + X0 + 4 * gx];
        #pragma unroll
        for (int jp = 0; jp < 4; ++jp) {
            const float4 v = {acc[jp][0], acc[jp][1], acc[jp][2], acc[jp][3]};
            *(float4*)&orow[(size_t)jp * H * W] = v;
        }
    }
}

extern "C" void kernel_launch(void* const* d_in, const int* in_sizes, int n_in,
                              void* d_out, int out_size, void* d_ws, size_t ws_size,
                              hipStream_t stream) {
    (void)in_sizes; (void)n_in; (void)d_ws; (void)ws_size; (void)out_size;
    const float* l0 = (const float*)d_in[0];
    const float* r0 = (const float*)d_in[1];
    const float* l1 = (const float*)d_in[2];
    const float* r1 = (const float*)d_in[3];
    const float* l2 = (const float*)d_in[4];
    const float* r2 = (const float*)d_in[5];
    // d_in[6] = max_disparity = 128 (fixed by harness shapes): D = 128, 64, 32.

    float* o0 = (float*)d_out;
    float* o1 = o0 + (size_t)2 * 128 * 256 * 512;  // (N, D0, H0, W0)
    float* o2 = o1 + (size_t)2 * 64 * 128 * 256;   // (N, D1, H1, W1)

    // level 0: N=2 C=32  H=256 W=512 D=128
    cost_volume_kernel<32, 256, 512, 128, 64, 256>
        <<<2 * 256 * (512 / 64), 256, 0, stream>>>(l0, r0, o0);
    // level 1: N=2 C=64  H=128 W=256 D=64
    cost_volume_kernel<64, 128, 256, 64, 64, 256>
        <<<2 * 128 * (256 / 64), 256, 0, stream>>>(l1, r1, o1);
    // level 2: N=2 C=96  H=64  W=128 D=32
    cost_volume_kernel<96, 64, 128, 32, 64, 256>
        <<<2 * 64 * (128 / 64), 256, 0, stream>>>(l2, r2, o2);
}

// Round 2
// 312.177 us; speedup vs baseline: 1.0135x; 1.0135x over previous
//
#include <hip/hip_runtime.h>

typedef __attribute__((ext_vector_type(8))) short bf16x8;
typedef __attribute__((ext_vector_type(4))) float f32x4;

static __device__ __forceinline__ unsigned short f32_to_bf16(float f) {
    unsigned int x = __float_as_uint(f);
    x += 0x7fffu + ((x >> 16) & 1u);   // round-to-nearest-even
    return (unsigned short)(x >> 16);
}

// Cost volume as banded GEMM: out[n,j,h,x] = sum_c l̂[c,x] r̂[c,x-j] = G[y=x-j, x]
// where G = R̂ᵀ·L̂. Per block: (n, h, x-tile TX). MFMA 16x16x32 bf16, K=32=C chunk.
// A = R̂ᵀ (M = RS = TX+D rows of y, K = C), B = L̂ (K = C, N = TX).
template<int C, int H, int W, int D, int TX, int NT>
__global__ __launch_bounds__(NT)
void cost_volume_mfma(const float* __restrict__ Lp, const float* __restrict__ Rp,
                      float* __restrict__ out)
{
    constexpr int RS = TX + D;        // staged y range: [X0-D, X0+TX)
    constexpr int AS = C + 8;         // bf16 row stride (pad: conflict-free b128 frags)
    constexpr int KC = C / 32;        // mfma k-steps
    constexpr int NW = NT / 64;       // waves per block = x-tiles per block
    static_assert(NW == TX / 16, "one wave per 16-wide x-tile");
    static_assert((AS * 2) % 16 == 0, "frag rows must be 16B aligned");

    constexpr int STAGE_F = C * (TX + RS);
    constexpr int OBUF_F  = D * TX;
    constexpr int UNION_F = STAGE_F > OBUF_F ? STAGE_F : OBUF_F;

    __shared__ __align__(16) float uni[UNION_F];          // fp32 stage, then out-buffer
    __shared__ __align__(16) unsigned short Abf[RS * AS]; // r̂ bf16, [y][c]
    __shared__ __align__(16) unsigned short Bbf[TX * AS]; // l̂ bf16, [x][c]

    float* lsf  = uni;            // [c][x], C x TX
    float* rsf  = uni + C * TX;   // [c][y], C x RS
    float* obuf = uni;            // [j][xl], D x TX (after norm phase)

    const int tid = threadIdx.x;
    constexpr int NXB = W / TX;
    const int bx = blockIdx.x;
    const int xb = bx % NXB;
    const int h  = (bx / NXB) % H;
    const int n  = bx / (NXB * H);
    const int X0 = xb * TX;

    // ---- stage L tile (coalesced float4) ----
    for (int i = tid; i < C * TX / 4; i += NT) {
        const int c = i / (TX / 4), v = i % (TX / 4);
        *(float4*)&lsf[c * TX + 4 * v] =
            *(const float4*)&Lp[(((size_t)n * C + c) * H + h) * W + X0 + 4 * v];
    }
    // ---- stage R tile, y in [X0-D, X0+TX), zero-fill y<0 ----
    for (int i = tid; i < C * RS / 4; i += NT) {
        const int c = i / (RS / 4), v = i % (RS / 4);
        const int y = X0 - D + 4 * v;
        const float* src = &Rp[(((size_t)n * C + c) * H + h) * W];
        float4 val;
        if (y >= 0) val = *(const float4*)&src[y];
        else {
            val.x = (y + 0) >= 0 ? src[y + 0] : 0.f;
            val.y = (y + 1) >= 0 ? src[y + 1] : 0.f;
            val.z = (y + 2) >= 0 ? src[y + 2] : 0.f;
            val.w = (y + 3) >= 0 ? src[y + 3] : 0.f;
        }
        *(float4*)&rsf[c * RS + 4 * v] = val;
    }
    __syncthreads();

    // ---- L2-normalize each column (values kept in registers), emit bf16
    //      transposed [spatial][c] with padded stride AS ----
    for (int col = tid; col < TX + RS; col += NT) {
        const float* src; int stride; unsigned short* dst;
        if (col < TX) { src = lsf + col;        stride = TX; dst = Bbf + col * AS; }
        else          { src = rsf + (col - TX); stride = RS; dst = Abf + (col - TX) * AS; }
        float v[C];
        float s = 0.f;
        #pragma unroll
        for (int c = 0; c < C; ++c) { v[c] = src[c * stride]; s += v[c] * v[c]; }
        const float inv = 1.0f / fmaxf(sqrtf(s), 1e-12f);
        #pragma unroll
        for (int c0 = 0; c0 < C; c0 += 8) {
            union { unsigned short us[8]; uint4 q; } p;
            #pragma unroll
            for (int k = 0; k < 8; ++k) p.us[k] = f32_to_bf16(v[c0 + k] * inv);
            *(uint4*)&dst[c0] = p.q;
        }
    }
    __syncthreads();

    // ---- banded MFMA sweep: wave w owns x-strip [16w, 16w+16) ----
    const int wave = tid >> 6, lane = tid & 63;
    const int colc = lane & 15, quad = lane >> 4;

    bf16x8 bfr[KC];
    #pragma unroll
    for (int kc = 0; kc < KC; ++kc)
        bfr[kc] = *(const bf16x8*)&Bbf[(wave * 16 + colc) * AS + kc * 32 + quad * 8];

    const int xl = wave * 16 + colc;
    // needed y-tiles for this x-strip: yt in [wave, wave + D/16] (exact band cover)
    #pragma unroll
    for (int t = 0; t <= D / 16; ++t) {
        const int yt = wave + t;
        f32x4 acc = {0.f, 0.f, 0.f, 0.f};
        #pragma unroll
        for (int kc = 0; kc < KC; ++kc) {
            const bf16x8 a =
                *(const bf16x8*)&Abf[(yt * 16 + colc) * AS + kc * 32 + quad * 8];
            acc = __builtin_amdgcn_mfma_f32_16x16x32_bf16(a, bfr[kc], acc, 0, 0, 0);
        }
        // D lane layout: col = lane&15 (x), row = quad*4 + r (y); j = x - y
        const int jb = D + xl - yt * 16 - quad * 4;
        #pragma unroll
        for (int r = 0; r < 4; ++r) {
            const int j = jb - r;
            if (j >= 0 && j < D) obuf[j * TX + xl] = acc[r];
        }
    }
    __syncthreads();

    // ---- coalesced float4 writeout of the band ----
    constexpr int JV = TX / 4;
    for (int i = tid; i < D * TX / 4; i += NT) {
        const int j = i / JV, c4 = i % JV;
        *(float4*)&out[(((size_t)n * D + j) * H + h) * W + X0 + 4 * c4] =
            *(const float4*)&obuf[j * TX + 4 * c4];
    }
}

extern "C" void kernel_launch(void* const* d_in, const int* in_sizes, int n_in,
                              void* d_out, int out_size, void* d_ws, size_t ws_size,
                              hipStream_t stream) {
    (void)in_sizes; (void)n_in; (void)d_ws; (void)ws_size; (void)out_size;
    const float* l0 = (const float*)d_in[0];
    const float* r0 = (const float*)d_in[1];
    const float* l1 = (const float*)d_in[2];
    const float* r1 = (const float*)d_in[3];
    const float* l2 = (const float*)d_in[4];
    const float* r2 = (const float*)d_in[5];
    // max_disparity = 128 fixed: D = 128, 64, 32 per level.

    float* o0 = (float*)d_out;
    float* o1 = o0 + (size_t)2 * 128 * 256 * 512;
    float* o2 = o1 + (size_t)2 * 64 * 128 * 256;

    // L0: C=32 H=256 W=512 D=128, TX=64, 256 thr  (LDS 52 KB, 3 blk/CU)
    cost_volume_mfma<32, 256, 512, 128, 64, 256>
        <<<2 * 256 * (512 / 64), 256, 0, stream>>>(l0, r0, o0);
    // L1: C=64 H=128 W=256 D=64, TX=32, 128 thr   (LDS 50 KB)
    cost_volume_mfma<64, 128, 256, 64, 32, 128>
        <<<2 * 128 * (256 / 32), 128, 0, stream>>>(l1, r1, o1);
    // L2: C=96 H=64 W=128 D=32, TX=32, 128 thr    (LDS 56 KB)
    cost_volume_mfma<96, 64, 128, 32, 32, 128>
        <<<2 * 64 * (128 / 32), 128, 0, stream>>>(l2, r2, o2);
}